// Round 3
// baseline (1892.652 us; speedup 1.0000x reference)
//
#include <hip/hip_runtime.h>
#include <math.h>

#define MULT 32
#define NSPEC 10
#define NGRAPH 16
#define INV_SC 0.05590169943749474f   /* 1/sqrt(32*10) */
#define INV32S 0.17677669529663687f   /* 1/sqrt(32) */

typedef unsigned short u16;
typedef __bf16 v8bf __attribute__((ext_vector_type(8)));
typedef float v4f __attribute__((ext_vector_type(4)));
typedef unsigned int v4u_t __attribute__((ext_vector_type(4)));

__device__ __forceinline__ u16 f2bf(float f) {
    unsigned int u = __builtin_bit_cast(unsigned int, f);
    unsigned int r = u + 0x7fffu + ((u >> 16) & 1u);
    return (u16)(r >> 16);
}

__device__ __forceinline__ v8bf frag16(const u16* p) {
    return __builtin_bit_cast(v8bf, *(const v4u_t*)p);
}

#define MFMA(a, b, c) __builtin_amdgcn_mfma_f32_16x16x32_bf16(a, b, c, 0, 0, 0)

// ---------------------------------------------------------------------------
// small utility kernels
// ---------------------------------------------------------------------------
__global__ void zero_kernel(float* __restrict__ p, int n) {
    int i = blockIdx.x * 256 + threadIdx.x;
    if (i < n) p[i] = 0.0f;
}

__global__ void count_kernel(const int* __restrict__ batch, float* __restrict__ cnt, int N) {
    __shared__ int bins[NGRAPH];
    int t = threadIdx.x;
    if (t < NGRAPH) bins[t] = 0;
    __syncthreads();
    int i = blockIdx.x * 256 + t;
    if (i < N) atomicAdd(&bins[batch[i]], 1);
    __syncthreads();
    if (t < NGRAPH && bins[t] > 0) atomicAdd(&cnt[t], (float)bins[t]);
}

// ---------------------------------------------------------------------------
// effective-weight precompute (fp32):
//  Weff[path,b][a,bb,z], path: 0=000, 1=110, 2=011, 3=101
// ---------------------------------------------------------------------------
__global__ void stageA_kernel(const float* __restrict__ w000, const float* __restrict__ w110,
                              const float* __restrict__ w011, const float* __restrict__ w101,
                              const float* __restrict__ lp0, const float* __restrict__ lp1,
                              float* __restrict__ tmp1) {
    int gid = blockIdx.x * 256 + threadIdx.x;
    int tslot = gid >> 15;
    int e = gid & 32767;
    int z = e & 31;
    int uv = e >> 5;
    int b = tslot >> 2, path = tslot & 3;
    const float* W = (path == 0 ? w000 : path == 1 ? w110 : path == 2 ? w011 : w101) + b * 32768;
    const float* L = ((path == 0 || path == 1) ? lp0 : lp1) + b * 1024;
    float scale = (path == 1) ? (1.0f / (8192.0f * 1.7320508075688772f)) : (1.0f / 8192.0f);
    const float* wr = W + uv * 32;
    float acc = 0.0f;
    for (int w = 0; w < 32; ++w) acc += wr[w] * L[w * 32 + z];
    tmp1[gid] = acc * scale;
}

__global__ void stageB_kernel(const float* __restrict__ ul0, const float* __restrict__ ul1,
                              const float* __restrict__ tmp1, float* __restrict__ tmp2) {
    int gid = blockIdx.x * 256 + threadIdx.x;
    int tslot = gid >> 15;
    int e = gid & 32767;
    int z = e & 31;
    int bb = (e >> 5) & 31;
    int u = e >> 10;
    int b = tslot >> 2, path = tslot & 3;
    const float* U = ((path == 0 || path == 3) ? ul0 : ul1) + b * 1024;
    const float* in = tmp1 + (size_t)tslot * 32768 + u * 1024 + z;
    float acc = 0.0f;
    for (int v = 0; v < 32; ++v) acc += U[bb * 32 + v] * in[v * 32];
    tmp2[gid] = acc;
}

__global__ void stageC_kernel(const float* __restrict__ hl0, const float* __restrict__ hl1,
                              const float* __restrict__ tmp2, float* __restrict__ Weff) {
    int gid = blockIdx.x * 256 + threadIdx.x;
    int tslot = gid >> 15;
    int e = gid & 32767;
    int z = e & 31;
    int bb = (e >> 5) & 31;
    int a = e >> 10;
    int b = tslot >> 2, path = tslot & 3;
    const float* H = ((path == 0 || path == 2) ? hl0 : hl1) + b * 1024;
    const float* in = tmp2 + (size_t)tslot * 32768 + bb * 32 + z;
    float acc = 0.0f;
    for (int u = 0; u < 32; ++u) acc += H[a * 32 + u] * in[u * 1024];
    Weff[gid] = acc;
}

// ---------------------------------------------------------------------------
// pack kernel: fp32 Weff / sc weights -> bf16, B-frag layouts (linear = col*32+k)
// per-b flat layout (151552 u16):
//  [0,32768):        W000T col=bb*32+z, k=a
//  [32768,65536):    W011T col=bb*32+z, k=a
//  [65536,98304):    W101T col=a*32+z,  k=bb
//  [98304,131072):   W110X col=a*32+z,  k=bb
//  [131072,141312):  WSC0P [s][col=z][k=a]  (x INV_SC)
//  [141312,151552):  WSC1P [s][col=z][k=a]  (x INV_SC)
// ---------------------------------------------------------------------------
__global__ void pack_kernel(const float* __restrict__ Weff,
                            const float* __restrict__ sc_w0, const float* __restrict__ sc_w1,
                            u16* __restrict__ packs, int total) {
    int gid = blockIdx.x * 256 + threadIdx.x;
    if (gid >= total) return;
    int b = gid / 151552;
    int e = gid - b * 151552;
    float v;
    if (e < 131072) {
        int which = e >> 15;          // 0:000 1:011 2:101 3:110
        int e2 = e & 32767;
        int k = e2 & 31;
        int z = (e2 >> 5) & 31;
        int hi = e2 >> 10;
        int path = (which == 0) ? 0 : (which == 1) ? 2 : (which == 2) ? 3 : 1;
        int a  = (which < 2) ? k  : hi;
        int bb = (which < 2) ? hi : k;
        v = Weff[(size_t)((b * 4 + path) * 32 + a) * 1024 + bb * 32 + z];
    } else {
        int e2 = e - 131072;
        int which = e2 / 10240;
        int e3 = e2 - which * 10240;
        int s = e3 >> 10, z = (e3 >> 5) & 31, a = e3 & 31;
        const float* S = which ? sc_w1 : sc_w0;
        v = S[(size_t)b * 10240 + a * 320 + s * 32 + z] * INV_SC;
    }
    packs[gid] = f2bf(v);
}

// ---------------------------------------------------------------------------
// MFMA TP + self-connection + stats kernel.  One WG (4 waves) per 32 nodes.
// Fused GEMM+stage2, no T materialization, no P matrix, no one-hot LDS.
// ---------------------------------------------------------------------------
__global__ __launch_bounds__(256, 3)
void tp_kernel(const float* __restrict__ hidden_b, const float* __restrict__ up,
               const u16* __restrict__ pk,
               const float* __restrict__ lp_b0,
               const int* __restrict__ species, const int* __restrict__ batch,
               float* __restrict__ S1, float* __restrict__ S2, float* __restrict__ V2,
               float* __restrict__ zout, int N) {
    constexpr int OFF_000 = 0, OFF_011 = 32768, OFF_101 = 65536, OFF_110 = 98304;
    constexpr int OFF_SC0 = 131072, OFF_SC1 = 141312;

    __shared__ __align__(16) char smem[49152];
    __shared__ int spec_l[32];
    __shared__ int bat_l[32];
    __shared__ float gs1[NGRAPH], gs2[NGRAPH], gv2[NGRAPH];

    u16* sh_bf = (u16*)smem;                 // [32][40] bf16, A-layout
    u16* su_bf = (u16*)(smem + 2560);        // [32][40]
    u16* vu_bf = (u16*)(smem + 5120);        // [3][32][40]
    u16* vh_bf = (u16*)(smem + 12800);       // [3][32][40]
    float* suT = (float*)(smem + 20480);     // [32 bb][32 n] fp32 (Y)
    float* vuT = (float*)(smem + 24576);     // [3][32][32]
    float* vhT = (float*)(smem + 36864);     // [3][32][32]
    float* red = (float*)smem;               // [4][16][132] fp32 (epilogue overlay)

    const int t = threadIdx.x;
    const int w = t >> 6, lane = t & 63, quad = lane >> 4, c16 = lane & 15;
    const int n0 = blockIdx.x * 32;
    const int nvalid = min(32, N - n0);

    if (t < NGRAPH) { gs1[t] = 0.f; gs2[t] = 0.f; gv2[t] = 0.f; }
    if (t < 32) {
        spec_l[t] = (t < nvalid) ? species[n0 + t] : -1;
        bat_l[t]  = (t < nvalid) ? batch[n0 + t] : 0;
    }
    for (int i = t; i < 4096; i += 256) {
        int n = i >> 7, col = i & 127;
        float hv = 0.f, uv = 0.f;
        if (n < nvalid) {
            hv = hidden_b[(size_t)(n0 + n) * 128 + col];
            uv = up[(size_t)(n0 + n) * 128 + col];
        }
        if (col < 32) {
            sh_bf[n * 40 + col] = f2bf(hv); su_bf[n * 40 + col] = f2bf(uv);
            suT[col * 32 + n] = uv;
        } else {
            int idx = col - 32, c = idx % 3, a = idx / 3;
            vh_bf[(c * 32 + n) * 40 + a] = f2bf(hv);
            vu_bf[(c * 32 + n) * 40 + a] = f2bf(uv);
            vhT[(c * 32 + a) * 32 + n] = hv;
            vuT[(c * 32 + a) * 32 + n] = uv;
        }
    }
    __syncthreads();

    const v4f z4 = {0.f, 0.f, 0.f, 0.f};
    v4f o0[2][2];                 // [half][zh] -> out0[node=half*16+quad*4+r][z=zh*16+c16]
    v4f o1[3][2][2];              // [c][half][zh]
#pragma unroll
    for (int h = 0; h < 2; ++h)
#pragma unroll
        for (int zh = 0; zh < 2; ++zh) {
            o0[h][zh] = z4;
#pragma unroll
            for (int c = 0; c < 3; ++c) o1[c][h][zh] = z4;
        }

    v8bf a_sh0 = frag16(sh_bf + c16 * 40 + quad * 8);
    v8bf a_sh1 = frag16(sh_bf + (16 + c16) * 40 + quad * 8);

    // ---- path 000: T=sh@W000 (col=bb*32+z), stage2 y=su ----
    {
        const u16* Wb = pk + OFF_000;
        v4f y0 = z4, y1 = z4;
#pragma unroll
        for (int t16 = 0; t16 < 16; ++t16) {
            v8bf bf = frag16(Wb + ((w * 16 + t16) * 16 + c16) * 32 + quad * 8);
            v4f C0 = MFMA(a_sh0, bf, z4);
            v4f C1 = MFMA(a_sh1, bf, z4);
            if (!(t16 & 1)) {
                int bb = w * 8 + (t16 >> 1);
                y0 = *(const v4f*)(suT + bb * 32 + quad * 4);
                y1 = *(const v4f*)(suT + bb * 32 + 16 + quad * 4);
            }
            int zh = t16 & 1;
#pragma unroll
            for (int r = 0; r < 4; ++r) {
                o0[0][zh][r] += C0[r] * y0[r];
                o0[1][zh][r] += C1[r] * y1[r];
            }
        }
    }
    // ---- path 011: T=sh@W011 (col=bb*32+z), stage2 y=vu[c] x3 ----
    {
        const u16* Wb = pk + OFF_011;
        v4f yu[3][2];
#pragma unroll
        for (int c = 0; c < 3; ++c) { yu[c][0] = z4; yu[c][1] = z4; }
#pragma unroll
        for (int t16 = 0; t16 < 16; ++t16) {
            v8bf bf = frag16(Wb + ((w * 16 + t16) * 16 + c16) * 32 + quad * 8);
            v4f C0 = MFMA(a_sh0, bf, z4);
            v4f C1 = MFMA(a_sh1, bf, z4);
            if (!(t16 & 1)) {
                int bb = w * 8 + (t16 >> 1);
#pragma unroll
                for (int c = 0; c < 3; ++c) {
                    yu[c][0] = *(const v4f*)(vuT + (c * 32 + bb) * 32 + quad * 4);
                    yu[c][1] = *(const v4f*)(vuT + (c * 32 + bb) * 32 + 16 + quad * 4);
                }
            }
            int zh = t16 & 1;
#pragma unroll
            for (int c = 0; c < 3; ++c)
#pragma unroll
                for (int r = 0; r < 4; ++r) {
                    o1[c][0][zh][r] += C0[r] * yu[c][0][r];
                    o1[c][1][zh][r] += C1[r] * yu[c][1][r];
                }
        }
    }
    // ---- path 101: T=su@W101 (col=a*32+z, k=bb), stage2 y=vh[c] x3 ----
    {
        v8bf a_su0 = frag16(su_bf + c16 * 40 + quad * 8);
        v8bf a_su1 = frag16(su_bf + (16 + c16) * 40 + quad * 8);
        const u16* Wb = pk + OFF_101;
        v4f yv[3][2];
#pragma unroll
        for (int c = 0; c < 3; ++c) { yv[c][0] = z4; yv[c][1] = z4; }
#pragma unroll
        for (int t16 = 0; t16 < 16; ++t16) {
            v8bf bf = frag16(Wb + ((w * 16 + t16) * 16 + c16) * 32 + quad * 8);
            v4f C0 = MFMA(a_su0, bf, z4);
            v4f C1 = MFMA(a_su1, bf, z4);
            if (!(t16 & 1)) {
                int aa = w * 8 + (t16 >> 1);
#pragma unroll
                for (int c = 0; c < 3; ++c) {
                    yv[c][0] = *(const v4f*)(vhT + (c * 32 + aa) * 32 + quad * 4);
                    yv[c][1] = *(const v4f*)(vhT + (c * 32 + aa) * 32 + 16 + quad * 4);
                }
            }
            int zh = t16 & 1;
#pragma unroll
            for (int c = 0; c < 3; ++c)
#pragma unroll
                for (int r = 0; r < 4; ++r) {
                    o1[c][0][zh][r] += C0[r] * yv[c][0][r];
                    o1[c][1][zh][r] += C1[r] * yv[c][1][r];
                }
        }
    }
    // ---- path 110 (T-form): per c, T_c=vu_c@W110X (col=a*32+z,k=bb), y=vh_c -> z0 ----
#pragma unroll
    for (int c = 0; c < 3; ++c) {
        v8bf av0 = frag16(vu_bf + (c * 32 + c16) * 40 + quad * 8);
        v8bf av1 = frag16(vu_bf + (c * 32 + 16 + c16) * 40 + quad * 8);
        const u16* Wb = pk + OFF_110;
        v4f y0 = z4, y1 = z4;
#pragma unroll
        for (int t16 = 0; t16 < 16; ++t16) {
            v8bf bf = frag16(Wb + ((w * 16 + t16) * 16 + c16) * 32 + quad * 8);
            v4f C0 = MFMA(av0, bf, z4);
            v4f C1 = MFMA(av1, bf, z4);
            if (!(t16 & 1)) {
                int aa = w * 8 + (t16 >> 1);
                y0 = *(const v4f*)(vhT + (c * 32 + aa) * 32 + quad * 4);
                y1 = *(const v4f*)(vhT + (c * 32 + aa) * 32 + 16 + quad * 4);
            }
            int zh = t16 & 1;
#pragma unroll
            for (int r = 0; r < 4; ++r) {
                o0[0][zh][r] += C0[r] * y0[r];
                o0[1][zh][r] += C1[r] * y1[r];
            }
        }
    }
    // ---- self connection: species-masked A-frags, species split over waves ----
    {
        const int s0 = (w < 2) ? w * 3 : 6 + (w - 2) * 2;
        const int ns = (w < 2) ? 3 : 2;
        v8bf zf = __builtin_bit_cast(v8bf, (v4u_t){0u, 0u, 0u, 0u});
        v8bf avh[3][2];
#pragma unroll
        for (int c = 0; c < 3; ++c) {
            avh[c][0] = frag16(vh_bf + (c * 32 + c16) * 40 + quad * 8);
            avh[c][1] = frag16(vh_bf + (c * 32 + 16 + c16) * 40 + quad * 8);
        }
        int sp0 = spec_l[c16], sp1 = spec_l[16 + c16];
        for (int si = s0; si < s0 + ns; ++si) {
            bool m0 = (sp0 == si), m1 = (sp1 == si);
#pragma unroll
            for (int zh = 0; zh < 2; ++zh) {
                int boff = (si * 32 + zh * 16 + c16) * 32 + quad * 8;
                v8bf bf0 = frag16(pk + OFF_SC0 + boff);
                v8bf bf1 = frag16(pk + OFF_SC1 + boff);
                v8bf am;
                am = m0 ? a_sh0 : zf;  o0[0][zh] = MFMA(am, bf0, o0[0][zh]);
                am = m1 ? a_sh1 : zf;  o0[1][zh] = MFMA(am, bf0, o0[1][zh]);
#pragma unroll
                for (int c = 0; c < 3; ++c) {
                    am = m0 ? avh[c][0] : zf;  o1[c][0][zh] = MFMA(am, bf1, o1[c][0][zh]);
                    am = m1 ? avh[c][1] : zf;  o1[c][1][zh] = MFMA(am, bf1, o1[c][1][zh]);
                }
            }
        }
    }

    // ---- epilogue: per half, cross-wave reduce through red (overlays staging) ----
#pragma unroll
    for (int h = 0; h < 2; ++h) {
        __syncthreads();
#pragma unroll
        for (int r = 0; r < 4; ++r) {
            int n = quad * 4 + r;
            float* row = red + (w * 16 + n) * 132;
            row[c16]      = o0[h][0][r];
            row[16 + c16] = o0[h][1][r];
#pragma unroll
            for (int c = 0; c < 3; ++c) {
                row[32 + c16 * 3 + c]        = o1[c][h][0][r];
                row[32 + (16 + c16) * 3 + c] = o1[c][h][1][r];
            }
        }
        __syncthreads();
        int n = t >> 4, seg = t & 15;
        v4f sa = z4, sb = z4;
#pragma unroll
        for (int ww = 0; ww < 4; ++ww) {
            const float* rp = red + (ww * 16 + n) * 132 + seg * 8;
            sa += *(const v4f*)rp;
            sb += *(const v4f*)(rp + 4);
        }
        float s1p = 0.f, s2p = 0.f, v2p = 0.f;
        if (seg < 4) {
            sa += *(const v4f*)(lp_b0 + seg * 8);
            sb += *(const v4f*)(lp_b0 + seg * 8 + 4);
            s1p = sa[0] + sa[1] + sa[2] + sa[3] + sb[0] + sb[1] + sb[2] + sb[3];
            s2p = sa[0]*sa[0] + sa[1]*sa[1] + sa[2]*sa[2] + sa[3]*sa[3]
                + sb[0]*sb[0] + sb[1]*sb[1] + sb[2]*sb[2] + sb[3]*sb[3];
        } else {
            v2p = sa[0]*sa[0] + sa[1]*sa[1] + sa[2]*sa[2] + sa[3]*sa[3]
                + sb[0]*sb[0] + sb[1]*sb[1] + sb[2]*sb[2] + sb[3]*sb[3];
        }
        int gn = h * 16 + n;
        if (gn < nvalid) {
            float* op = zout + (size_t)(n0 + gn) * 128 + seg * 8;
            *(v4f*)op = sa;
            *(v4f*)(op + 4) = sb;
        }
#pragma unroll
        for (int off = 8; off >= 1; off >>= 1) {
            s1p += __shfl_xor(s1p, off, 16);
            s2p += __shfl_xor(s2p, off, 16);
            v2p += __shfl_xor(v2p, off, 16);
        }
        if (seg == 0 && gn < nvalid) {
            int g = bat_l[gn];
            atomicAdd(&gs1[g], s1p);
            atomicAdd(&gs2[g], s2p);
            atomicAdd(&gv2[g], v2p);
        }
    }
    __syncthreads();
    if (t < NGRAPH) {
        if (gs1[t] != 0.f) atomicAdd(&S1[t], gs1[t]);
        if (gs2[t] != 0.f) atomicAdd(&S2[t], gs2[t]);
        if (gv2[t] != 0.f) atomicAdd(&V2[t], gv2[t]);
    }
}

// ---------------------------------------------------------------------------
// LayerNorm + skip kernel (in-place on z written by tp_kernel)
// ---------------------------------------------------------------------------
__global__ __launch_bounds__(256)
void norm_kernel(const float* __restrict__ hidden_b, float* __restrict__ out_b,
                 const float* __restrict__ skw0, const float* __restrict__ skb0,
                 const float* __restrict__ skw1,
                 const float* __restrict__ lnw0, const float* __restrict__ lnb0,
                 const float* __restrict__ lnw1,
                 const int* __restrict__ batch,
                 const float* __restrict__ S1, const float* __restrict__ S2,
                 const float* __restrict__ V2, const float* __restrict__ cnt, int N) {
    __shared__ __align__(16) float sh_l[8][32];
    __shared__ __align__(16) float vh_l[8][96];
    const int t = threadIdx.x, z = t & 31, nl = t >> 5;
    const int n0 = blockIdx.x * 8;
    for (int i = t; i < 8 * 128; i += 256) {
        int n = i >> 7, col = i & 127;
        float v = (n0 + n < N) ? hidden_b[(size_t)(n0 + n) * 128 + col] : 0.f;
        if (col < 32) sh_l[n][col] = v; else vh_l[n][col - 32] = v;
    }
    __syncthreads();
    const int n = n0 + nl;
    if (n >= N) return;

    float sk0 = 0.f, s1 = 0.f, s2 = 0.f, s3 = 0.f;
    for (int a = 0; a < 32; ++a) {
        float w0 = skw0[a * 32 + z];
        float w1 = skw1[a * 32 + z];
        sk0 += sh_l[nl][a] * w0;
        s1 += vh_l[nl][a * 3 + 0] * w1;
        s2 += vh_l[nl][a * 3 + 1] * w1;
        s3 += vh_l[nl][a * 3 + 2] * w1;
    }
    int g = batch[n];
    float cM = fmaxf(cnt[g], 1.0f) * 32.0f;
    float mean = S1[g] / cM;
    float var = fmaxf(S2[g] / cM - mean * mean, 0.0f);
    float rs = rsqrtf(var + 1e-5f);
    float rv = rsqrtf(fmaxf(V2[g] / cM, 0.0f) + 1e-5f);

    size_t base = (size_t)n * 128;
    float z0 = out_b[base + z];
    out_b[base + z] = (z0 - mean) * rs * lnw0[z] + lnb0[z] + sk0 * INV32S + skb0[z];
    float lw = lnw1[z] * rv;
    float x0 = out_b[base + 32 + z * 3 + 0];
    float x1 = out_b[base + 32 + z * 3 + 1];
    float x2 = out_b[base + 32 + z * 3 + 2];
    out_b[base + 32 + z * 3 + 0] = x0 * lw + s1 * INV32S;
    out_b[base + 32 + z * 3 + 1] = x1 * lw + s2 * INV32S;
    out_b[base + 32 + z * 3 + 2] = x2 * lw + s3 * INV32S;
}

// ---------------------------------------------------------------------------
extern "C" void kernel_launch(void* const* d_in, const int* in_sizes, int n_in,
                              void* d_out, int out_size, void* d_ws, size_t ws_size,
                              hipStream_t stream) {
    const float* hidden = (const float*)d_in[0];
    const float* up0    = (const float*)d_in[1];
    const float* hl_w0  = (const float*)d_in[2];
    const float* hl_w1  = (const float*)d_in[3];
    const float* ul_w0  = (const float*)d_in[4];
    const float* ul_w1  = (const float*)d_in[5];
    const float* w000   = (const float*)d_in[6];
    const float* w110   = (const float*)d_in[7];
    const float* w011   = (const float*)d_in[8];
    const float* w101   = (const float*)d_in[9];
    const float* lp_w0  = (const float*)d_in[10];
    const float* lp_b0  = (const float*)d_in[11];
    const float* lp_w1  = (const float*)d_in[12];
    const float* sc_w0  = (const float*)d_in[13];
    const float* sc_w1  = (const float*)d_in[14];
    const float* ln_w0  = (const float*)d_in[15];
    const float* ln_b0  = (const float*)d_in[16];
    const float* ln_w1  = (const float*)d_in[17];
    const float* sk_w0  = (const float*)d_in[18];
    const float* sk_b0  = (const float*)d_in[19];
    const float* sk_w1  = (const float*)d_in[20];
    const int* species  = (const int*)d_in[21];
    const int* batch    = (const int*)d_in[22];
    float* out = (float*)d_out;

    const int N = in_sizes[21];
    const int B = in_sizes[0] / (N * 128);

    float* ws = (float*)d_ws;
    float* Weff = ws;                                  // B*4*32768 fp32
    float* tmp1 = Weff + (size_t)B * 4 * 32768;        // reused as bf16 packs
    float* tmp2 = tmp1 + (size_t)B * 4 * 32768;
    float* stats = tmp2 + (size_t)B * 4 * 32768;
    float* cnt = stats;
    float* S1 = stats + NGRAPH;
    float* S2 = S1 + B * NGRAPH;
    float* V2 = S2 + B * NGRAPH;
    int statn = NGRAPH + 3 * B * NGRAPH;

    zero_kernel<<<1, 256, 0, stream>>>(stats, statn);
    count_kernel<<<(N + 255) / 256, 256, 0, stream>>>(batch, cnt, N);

    int nb = B * 4 * 32768 / 256;
    stageA_kernel<<<nb, 256, 0, stream>>>(w000, w110, w011, w101, lp_w0, lp_w1, tmp1);
    stageB_kernel<<<nb, 256, 0, stream>>>(ul_w0, ul_w1, tmp1, tmp2);
    stageC_kernel<<<nb, 256, 0, stream>>>(hl_w0, hl_w1, tmp2, Weff);

    u16* packs = (u16*)tmp1;                           // tmp1 dead after stageB
    int ptotal = B * 151552;
    pack_kernel<<<(ptotal + 255) / 256, 256, 0, stream>>>(Weff, sc_w0, sc_w1, packs, ptotal);

    for (int b = 0; b < B; ++b) {
        const float* up = (b == 0) ? up0 : out + (size_t)(b - 1) * N * 128;
        const u16* pb = packs + (size_t)b * 151552;
        tp_kernel<<<(N + 31) / 32, 256, 0, stream>>>(
            hidden + (size_t)b * N * 128, up, pb,
            lp_b0 + b * MULT, species, batch,
            S1 + b * NGRAPH, S2 + b * NGRAPH, V2 + b * NGRAPH,
            out + (size_t)b * N * 128, N);
        norm_kernel<<<(N + 7) / 8, 256, 0, stream>>>(
            hidden + (size_t)b * N * 128, out + (size_t)b * N * 128,
            sk_w0 + b * 1024, sk_b0 + b * MULT, sk_w1 + b * 1024,
            ln_w0 + b * MULT, ln_b0 + b * MULT, ln_w1 + b * MULT,
            batch, S1 + b * NGRAPH, S2 + b * NGRAPH, V2 + b * NGRAPH, cnt, N);
    }
}

// Round 4
// 416.659 us; speedup vs baseline: 4.5424x; 4.5424x over previous
//
#include <hip/hip_runtime.h>
#include <math.h>

#define MULT 32
#define NSPEC 10
#define NGRAPH 16
#define INV_SC 0.05590169943749474f   /* 1/sqrt(32*10) */
#define INV32S 0.17677669529663687f   /* 1/sqrt(32) */

typedef unsigned short u16;
typedef __bf16 v8bf __attribute__((ext_vector_type(8)));
typedef float v4f __attribute__((ext_vector_type(4)));
typedef unsigned int v4u_t __attribute__((ext_vector_type(4)));

__device__ __forceinline__ u16 f2bf(float f) {
    unsigned int u = __builtin_bit_cast(unsigned int, f);
    unsigned int r = u + 0x7fffu + ((u >> 16) & 1u);
    return (u16)(r >> 16);
}

__device__ __forceinline__ v8bf frag16(const u16* p) {
    return __builtin_bit_cast(v8bf, *(const v4u_t*)p);
}

#define MFMA(a, b, c) __builtin_amdgcn_mfma_f32_16x16x32_bf16(a, b, c, 0, 0, 0)

// ---------------------------------------------------------------------------
// small utility kernels
// ---------------------------------------------------------------------------
__global__ void zero_kernel(float* __restrict__ p, int n) {
    int i = blockIdx.x * 256 + threadIdx.x;
    if (i < n) p[i] = 0.0f;
}

__global__ void count_kernel(const int* __restrict__ batch, float* __restrict__ cnt, int N) {
    __shared__ int bins[NGRAPH];
    int t = threadIdx.x;
    if (t < NGRAPH) bins[t] = 0;
    __syncthreads();
    int i = blockIdx.x * 256 + t;
    if (i < N) atomicAdd(&bins[batch[i]], 1);
    __syncthreads();
    if (t < NGRAPH && bins[t] > 0) atomicAdd(&cnt[t], (float)bins[t]);
}

// ---------------------------------------------------------------------------
// effective-weight precompute (fp32):
//  Weff[path,b][a,bb,z], path: 0=000, 1=110, 2=011, 3=101
// ---------------------------------------------------------------------------
__global__ void stageA_kernel(const float* __restrict__ w000, const float* __restrict__ w110,
                              const float* __restrict__ w011, const float* __restrict__ w101,
                              const float* __restrict__ lp0, const float* __restrict__ lp1,
                              float* __restrict__ tmp1) {
    int gid = blockIdx.x * 256 + threadIdx.x;
    int tslot = gid >> 15;
    int e = gid & 32767;
    int z = e & 31;
    int uv = e >> 5;
    int b = tslot >> 2, path = tslot & 3;
    const float* W = (path == 0 ? w000 : path == 1 ? w110 : path == 2 ? w011 : w101) + b * 32768;
    const float* L = ((path == 0 || path == 1) ? lp0 : lp1) + b * 1024;
    float scale = (path == 1) ? (1.0f / (8192.0f * 1.7320508075688772f)) : (1.0f / 8192.0f);
    const float* wr = W + uv * 32;
    float acc = 0.0f;
    for (int w = 0; w < 32; ++w) acc += wr[w] * L[w * 32 + z];
    tmp1[gid] = acc * scale;
}

__global__ void stageB_kernel(const float* __restrict__ ul0, const float* __restrict__ ul1,
                              const float* __restrict__ tmp1, float* __restrict__ tmp2) {
    int gid = blockIdx.x * 256 + threadIdx.x;
    int tslot = gid >> 15;
    int e = gid & 32767;
    int z = e & 31;
    int bb = (e >> 5) & 31;
    int u = e >> 10;
    int b = tslot >> 2, path = tslot & 3;
    const float* U = ((path == 0 || path == 3) ? ul0 : ul1) + b * 1024;
    const float* in = tmp1 + (size_t)tslot * 32768 + u * 1024 + z;
    float acc = 0.0f;
    for (int v = 0; v < 32; ++v) acc += U[bb * 32 + v] * in[v * 32];
    tmp2[gid] = acc;
}

__global__ void stageC_kernel(const float* __restrict__ hl0, const float* __restrict__ hl1,
                              const float* __restrict__ tmp2, float* __restrict__ Weff) {
    int gid = blockIdx.x * 256 + threadIdx.x;
    int tslot = gid >> 15;
    int e = gid & 32767;
    int z = e & 31;
    int bb = (e >> 5) & 31;
    int a = e >> 10;
    int b = tslot >> 2, path = tslot & 3;
    const float* H = ((path == 0 || path == 2) ? hl0 : hl1) + b * 1024;
    const float* in = tmp2 + (size_t)tslot * 32768 + bb * 32 + z;
    float acc = 0.0f;
    for (int u = 0; u < 32; ++u) acc += H[a * 32 + u] * in[u * 1024];
    Weff[gid] = acc;
}

// ---------------------------------------------------------------------------
// pack kernel: fp32 Weff / sc weights -> bf16, B-frag layouts (linear = col*32+k)
// per-b flat layout (151552 u16):
//  [0,32768):        W000T col=bb*32+z, k=a
//  [32768,65536):    W011T col=bb*32+z, k=a
//  [65536,98304):    W101T col=a*32+z,  k=bb
//  [98304,131072):   W110X col=a*32+z,  k=bb
//  [131072,141312):  WSC0P [s][col=z][k=a]  (x INV_SC)
//  [141312,151552):  WSC1P [s][col=z][k=a]  (x INV_SC)
// ---------------------------------------------------------------------------
__global__ void pack_kernel(const float* __restrict__ Weff,
                            const float* __restrict__ sc_w0, const float* __restrict__ sc_w1,
                            u16* __restrict__ packs, int total) {
    int gid = blockIdx.x * 256 + threadIdx.x;
    if (gid >= total) return;
    int b = gid / 151552;
    int e = gid - b * 151552;
    float v;
    if (e < 131072) {
        int which = e >> 15;          // 0:000 1:011 2:101 3:110
        int e2 = e & 32767;
        int k = e2 & 31;
        int z = (e2 >> 5) & 31;
        int hi = e2 >> 10;
        int path = (which == 0) ? 0 : (which == 1) ? 2 : (which == 2) ? 3 : 1;
        int a  = (which < 2) ? k  : hi;
        int bb = (which < 2) ? hi : k;
        v = Weff[(size_t)((b * 4 + path) * 32 + a) * 1024 + bb * 32 + z];
    } else {
        int e2 = e - 131072;
        int which = e2 / 10240;
        int e3 = e2 - which * 10240;
        int s = e3 >> 10, z = (e3 >> 5) & 31, a = e3 & 31;
        const float* S = which ? sc_w1 : sc_w0;
        v = S[(size_t)b * 10240 + a * 320 + s * 32 + z] * INV_SC;
    }
    packs[gid] = f2bf(v);
}

// ---------------------------------------------------------------------------
// MFMA TP + self-connection + stats kernel.  One WG (4 waves) per 16 nodes.
// Fused GEMM+stage2; minimal accumulator state (8 v4f); occupancy pinned to
// 4 waves/EU so the allocator has a 128-reg budget and no incentive to spill.
// ---------------------------------------------------------------------------
__attribute__((amdgpu_waves_per_eu(4, 4)))
__global__ __launch_bounds__(256)
void tp_kernel(const float* __restrict__ hidden_b, const float* __restrict__ up,
               const u16* __restrict__ pk,
               const float* __restrict__ lp_b0,
               const int* __restrict__ species, const int* __restrict__ batch,
               float* __restrict__ S1, float* __restrict__ S2, float* __restrict__ V2,
               float* __restrict__ zout, int N) {
    constexpr int OFF_000 = 0, OFF_011 = 32768, OFF_101 = 65536, OFF_110 = 98304;
    constexpr int OFF_SC0 = 131072, OFF_SC1 = 141312;

    __shared__ __align__(16) char smem[33792];
    __shared__ int spec_l[16];
    __shared__ int bat_l[16];
    __shared__ float gs1[NGRAPH], gs2[NGRAPH], gv2[NGRAPH];

    u16* sh_bf = (u16*)smem;                 // [16][40] bf16, A-layout
    u16* su_bf = (u16*)(smem + 1280);        // [16][40]
    u16* vu_bf = (u16*)(smem + 2560);        // [3][16][40]
    u16* vh_bf = (u16*)(smem + 6400);        // [3][16][40]
    float* suT = (float*)(smem + 10240);     // [32 bb][16 n] fp32 (Y)
    float* vuT = (float*)(smem + 12288);     // [3][32][16]
    float* vhT = (float*)(smem + 18432);     // [3][32][16]
    float* red = (float*)smem;               // [4][16][132] fp32 (epilogue overlay)

    const int t = threadIdx.x;
    const int w = t >> 6, lane = t & 63, quad = lane >> 4, c16 = lane & 15;
    const int n0 = blockIdx.x * 16;
    const int nvalid = min(16, N - n0);

    if (t < NGRAPH) { gs1[t] = 0.f; gs2[t] = 0.f; gv2[t] = 0.f; }
    if (t < 16) {
        spec_l[t] = (t < nvalid) ? species[n0 + t] : -1;
        bat_l[t]  = (t < nvalid) ? batch[n0 + t] : 0;
    }
    for (int i = t; i < 2048; i += 256) {
        int n = i >> 7, col = i & 127;
        float hv = 0.f, uv = 0.f;
        if (n < nvalid) {
            hv = hidden_b[(size_t)(n0 + n) * 128 + col];
            uv = up[(size_t)(n0 + n) * 128 + col];
        }
        if (col < 32) {
            sh_bf[n * 40 + col] = f2bf(hv); su_bf[n * 40 + col] = f2bf(uv);
            suT[col * 16 + n] = uv;
        } else {
            int idx = col - 32, c = idx % 3, a = idx / 3;
            vh_bf[(c * 16 + n) * 40 + a] = f2bf(hv);
            vu_bf[(c * 16 + n) * 40 + a] = f2bf(uv);
            vhT[(c * 32 + a) * 16 + n] = hv;
            vuT[(c * 32 + a) * 16 + n] = uv;
        }
    }
    __syncthreads();

    const v4f z4 = {0.f, 0.f, 0.f, 0.f};
    v4f o0[2];                    // [zh] -> out0[node=quad*4+r][z=zh*16+c16]
    v4f o1[3][2];                 // [c][zh]
    o0[0] = z4; o0[1] = z4;
#pragma unroll
    for (int c = 0; c < 3; ++c) { o1[c][0] = z4; o1[c][1] = z4; }

    v8bf a_sh = frag16(sh_bf + c16 * 40 + quad * 8);

    // ---- path 000: T=sh@W000 (col=bb*32+z), stage2 y=su ----
    {
        const u16* Wb = pk + OFF_000 + (w * 16 * 16 + c16) * 32 + quad * 8;
#pragma unroll 4
        for (int th = 0; th < 8; ++th) {
            int bb = w * 8 + th;
            v4f y = *(const v4f*)(suT + bb * 16 + quad * 4);
            v8bf bf0 = frag16(Wb + (th * 2) * 512);
            v8bf bf1 = frag16(Wb + (th * 2 + 1) * 512);
            v4f C0 = MFMA(a_sh, bf0, z4);
            v4f C1 = MFMA(a_sh, bf1, z4);
#pragma unroll
            for (int r = 0; r < 4; ++r) {
                o0[0][r] += C0[r] * y[r];
                o0[1][r] += C1[r] * y[r];
            }
        }
    }
    // ---- path 011: T=sh@W011 (col=bb*32+z), stage2 y=vu[c] x3 ----
    {
        const u16* Wb = pk + OFF_011 + (w * 16 * 16 + c16) * 32 + quad * 8;
#pragma unroll 2
        for (int th = 0; th < 8; ++th) {
            int bb = w * 8 + th;
            v8bf bf0 = frag16(Wb + (th * 2) * 512);
            v8bf bf1 = frag16(Wb + (th * 2 + 1) * 512);
            v4f C0 = MFMA(a_sh, bf0, z4);
            v4f C1 = MFMA(a_sh, bf1, z4);
#pragma unroll
            for (int c = 0; c < 3; ++c) {
                v4f y = *(const v4f*)(vuT + (c * 32 + bb) * 16 + quad * 4);
#pragma unroll
                for (int r = 0; r < 4; ++r) {
                    o1[c][0][r] += C0[r] * y[r];
                    o1[c][1][r] += C1[r] * y[r];
                }
            }
        }
    }
    // ---- path 101: T=su@W101 (col=a*32+z, k=bb), stage2 y=vh[c] x3 ----
    {
        v8bf a_su = frag16(su_bf + c16 * 40 + quad * 8);
        const u16* Wb = pk + OFF_101 + (w * 16 * 16 + c16) * 32 + quad * 8;
#pragma unroll 2
        for (int th = 0; th < 8; ++th) {
            int aa = w * 8 + th;
            v8bf bf0 = frag16(Wb + (th * 2) * 512);
            v8bf bf1 = frag16(Wb + (th * 2 + 1) * 512);
            v4f C0 = MFMA(a_su, bf0, z4);
            v4f C1 = MFMA(a_su, bf1, z4);
#pragma unroll
            for (int c = 0; c < 3; ++c) {
                v4f y = *(const v4f*)(vhT + (c * 32 + aa) * 16 + quad * 4);
#pragma unroll
                for (int r = 0; r < 4; ++r) {
                    o1[c][0][r] += C0[r] * y[r];
                    o1[c][1][r] += C1[r] * y[r];
                }
            }
        }
    }
    // ---- path 110 (T-form): per c, T_c=vu_c@W110X (col=a*32+z,k=bb), y=vh_c ----
#pragma unroll
    for (int c = 0; c < 3; ++c) {
        v8bf av = frag16(vu_bf + (c * 16 + c16) * 40 + quad * 8);
        const u16* Wb = pk + OFF_110 + (w * 16 * 16 + c16) * 32 + quad * 8;
#pragma unroll 4
        for (int th = 0; th < 8; ++th) {
            int aa = w * 8 + th;
            v4f y = *(const v4f*)(vhT + (c * 32 + aa) * 16 + quad * 4);
            v8bf bf0 = frag16(Wb + (th * 2) * 512);
            v8bf bf1 = frag16(Wb + (th * 2 + 1) * 512);
            v4f C0 = MFMA(av, bf0, z4);
            v4f C1 = MFMA(av, bf1, z4);
#pragma unroll
            for (int r = 0; r < 4; ++r) {
                o0[0][r] += C0[r] * y[r];
                o0[1][r] += C1[r] * y[r];
            }
        }
    }
    // ---- self connection: species-masked A-frags, species split over waves ----
    {
        const int s0 = (w < 2) ? w * 3 : 6 + (w - 2) * 2;
        const int ns = (w < 2) ? 3 : 2;
        v8bf zf = __builtin_bit_cast(v8bf, (v4u_t){0u, 0u, 0u, 0u});
        int sp = spec_l[c16];
        for (int si = s0; si < s0 + ns; ++si) {
            bool m = (sp == si);
            v8bf ash_m = m ? a_sh : zf;
#pragma unroll
            for (int zh = 0; zh < 2; ++zh) {
                int boff = (si * 32 + zh * 16 + c16) * 32 + quad * 8;
                v8bf bf0 = frag16(pk + OFF_SC0 + boff);
                v8bf bf1 = frag16(pk + OFF_SC1 + boff);
                o0[zh] = MFMA(ash_m, bf0, o0[zh]);
#pragma unroll
                for (int c = 0; c < 3; ++c) {
                    v8bf av = frag16(vh_bf + (c * 16 + c16) * 40 + quad * 8);
                    v8bf am = m ? av : zf;
                    o1[c][zh] = MFMA(am, bf1, o1[c][zh]);
                }
            }
        }
    }

    // ---- epilogue: cross-wave reduce through red (overlays staging) ----
    __syncthreads();
#pragma unroll
    for (int r = 0; r < 4; ++r) {
        int n = quad * 4 + r;
        float* row = red + (w * 16 + n) * 132;
        row[c16]      = o0[0][r];
        row[16 + c16] = o0[1][r];
#pragma unroll
        for (int c = 0; c < 3; ++c) {
            row[32 + c16 * 3 + c]        = o1[c][0][r];
            row[32 + (16 + c16) * 3 + c] = o1[c][1][r];
        }
    }
    __syncthreads();
    {
        int n = t >> 4, seg = t & 15;
        v4f sa = z4, sb = z4;
#pragma unroll
        for (int ww = 0; ww < 4; ++ww) {
            const float* rp = red + (ww * 16 + n) * 132 + seg * 8;
            sa += *(const v4f*)rp;
            sb += *(const v4f*)(rp + 4);
        }
        float s1p = 0.f, s2p = 0.f, v2p = 0.f;
        if (seg < 4) {
            sa += *(const v4f*)(lp_b0 + seg * 8);
            sb += *(const v4f*)(lp_b0 + seg * 8 + 4);
            s1p = sa[0] + sa[1] + sa[2] + sa[3] + sb[0] + sb[1] + sb[2] + sb[3];
            s2p = sa[0]*sa[0] + sa[1]*sa[1] + sa[2]*sa[2] + sa[3]*sa[3]
                + sb[0]*sb[0] + sb[1]*sb[1] + sb[2]*sb[2] + sb[3]*sb[3];
        } else {
            v2p = sa[0]*sa[0] + sa[1]*sa[1] + sa[2]*sa[2] + sa[3]*sa[3]
                + sb[0]*sb[0] + sb[1]*sb[1] + sb[2]*sb[2] + sb[3]*sb[3];
        }
        if (n < nvalid) {
            float* op = zout + (size_t)(n0 + n) * 128 + seg * 8;
            *(v4f*)op = sa;
            *(v4f*)(op + 4) = sb;
        }
#pragma unroll
        for (int off = 8; off >= 1; off >>= 1) {
            s1p += __shfl_xor(s1p, off, 16);
            s2p += __shfl_xor(s2p, off, 16);
            v2p += __shfl_xor(v2p, off, 16);
        }
        if (seg == 0 && n < nvalid) {
            int g = bat_l[n];
            atomicAdd(&gs1[g], s1p);
            atomicAdd(&gs2[g], s2p);
            atomicAdd(&gv2[g], v2p);
        }
    }
    __syncthreads();
    if (t < NGRAPH) {
        if (gs1[t] != 0.f) atomicAdd(&S1[t], gs1[t]);
        if (gs2[t] != 0.f) atomicAdd(&S2[t], gs2[t]);
        if (gv2[t] != 0.f) atomicAdd(&V2[t], gv2[t]);
    }
}

// ---------------------------------------------------------------------------
// LayerNorm + skip kernel (in-place on z written by tp_kernel)
// ---------------------------------------------------------------------------
__global__ __launch_bounds__(256)
void norm_kernel(const float* __restrict__ hidden_b, float* __restrict__ out_b,
                 const float* __restrict__ skw0, const float* __restrict__ skb0,
                 const float* __restrict__ skw1,
                 const float* __restrict__ lnw0, const float* __restrict__ lnb0,
                 const float* __restrict__ lnw1,
                 const int* __restrict__ batch,
                 const float* __restrict__ S1, const float* __restrict__ S2,
                 const float* __restrict__ V2, const float* __restrict__ cnt, int N) {
    __shared__ __align__(16) float sh_l[8][32];
    __shared__ __align__(16) float vh_l[8][96];
    const int t = threadIdx.x, z = t & 31, nl = t >> 5;
    const int n0 = blockIdx.x * 8;
    for (int i = t; i < 8 * 128; i += 256) {
        int n = i >> 7, col = i & 127;
        float v = (n0 + n < N) ? hidden_b[(size_t)(n0 + n) * 128 + col] : 0.f;
        if (col < 32) sh_l[n][col] = v; else vh_l[n][col - 32] = v;
    }
    __syncthreads();
    const int n = n0 + nl;
    if (n >= N) return;

    float sk0 = 0.f, s1 = 0.f, s2 = 0.f, s3 = 0.f;
    for (int a = 0; a < 32; ++a) {
        float w0 = skw0[a * 32 + z];
        float w1 = skw1[a * 32 + z];
        sk0 += sh_l[nl][a] * w0;
        s1 += vh_l[nl][a * 3 + 0] * w1;
        s2 += vh_l[nl][a * 3 + 1] * w1;
        s3 += vh_l[nl][a * 3 + 2] * w1;
    }
    int g = batch[n];
    float cM = fmaxf(cnt[g], 1.0f) * 32.0f;
    float mean = S1[g] / cM;
    float var = fmaxf(S2[g] / cM - mean * mean, 0.0f);
    float rs = rsqrtf(var + 1e-5f);
    float rv = rsqrtf(fmaxf(V2[g] / cM, 0.0f) + 1e-5f);

    size_t base = (size_t)n * 128;
    float z0 = out_b[base + z];
    out_b[base + z] = (z0 - mean) * rs * lnw0[z] + lnb0[z] + sk0 * INV32S + skb0[z];
    float lw = lnw1[z] * rv;
    float x0 = out_b[base + 32 + z * 3 + 0];
    float x1 = out_b[base + 32 + z * 3 + 1];
    float x2 = out_b[base + 32 + z * 3 + 2];
    out_b[base + 32 + z * 3 + 0] = x0 * lw + s1 * INV32S;
    out_b[base + 32 + z * 3 + 1] = x1 * lw + s2 * INV32S;
    out_b[base + 32 + z * 3 + 2] = x2 * lw + s3 * INV32S;
}

// ---------------------------------------------------------------------------
extern "C" void kernel_launch(void* const* d_in, const int* in_sizes, int n_in,
                              void* d_out, int out_size, void* d_ws, size_t ws_size,
                              hipStream_t stream) {
    const float* hidden = (const float*)d_in[0];
    const float* up0    = (const float*)d_in[1];
    const float* hl_w0  = (const float*)d_in[2];
    const float* hl_w1  = (const float*)d_in[3];
    const float* ul_w0  = (const float*)d_in[4];
    const float* ul_w1  = (const float*)d_in[5];
    const float* w000   = (const float*)d_in[6];
    const float* w110   = (const float*)d_in[7];
    const float* w011   = (const float*)d_in[8];
    const float* w101   = (const float*)d_in[9];
    const float* lp_w0  = (const float*)d_in[10];
    const float* lp_b0  = (const float*)d_in[11];
    const float* lp_w1  = (const float*)d_in[12];
    const float* sc_w0  = (const float*)d_in[13];
    const float* sc_w1  = (const float*)d_in[14];
    const float* ln_w0  = (const float*)d_in[15];
    const float* ln_b0  = (const float*)d_in[16];
    const float* ln_w1  = (const float*)d_in[17];
    const float* sk_w0  = (const float*)d_in[18];
    const float* sk_b0  = (const float*)d_in[19];
    const float* sk_w1  = (const float*)d_in[20];
    const int* species  = (const int*)d_in[21];
    const int* batch    = (const int*)d_in[22];
    float* out = (float*)d_out;

    const int N = in_sizes[21];
    const int B = in_sizes[0] / (N * 128);

    float* ws = (float*)d_ws;
    float* Weff = ws;                                  // B*4*32768 fp32
    float* tmp1 = Weff + (size_t)B * 4 * 32768;        // reused as bf16 packs
    float* tmp2 = tmp1 + (size_t)B * 4 * 32768;
    float* stats = tmp2 + (size_t)B * 4 * 32768;
    float* cnt = stats;
    float* S1 = stats + NGRAPH;
    float* S2 = S1 + B * NGRAPH;
    float* V2 = S2 + B * NGRAPH;
    int statn = NGRAPH + 3 * B * NGRAPH;

    zero_kernel<<<1, 256, 0, stream>>>(stats, statn);
    count_kernel<<<(N + 255) / 256, 256, 0, stream>>>(batch, cnt, N);

    int nb = B * 4 * 32768 / 256;
    stageA_kernel<<<nb, 256, 0, stream>>>(w000, w110, w011, w101, lp_w0, lp_w1, tmp1);
    stageB_kernel<<<nb, 256, 0, stream>>>(ul_w0, ul_w1, tmp1, tmp2);
    stageC_kernel<<<nb, 256, 0, stream>>>(hl_w0, hl_w1, tmp2, Weff);

    u16* packs = (u16*)tmp1;                           // tmp1 dead after stageB
    int ptotal = B * 151552;
    pack_kernel<<<(ptotal + 255) / 256, 256, 0, stream>>>(Weff, sc_w0, sc_w1, packs, ptotal);

    for (int b = 0; b < B; ++b) {
        const float* up = (b == 0) ? up0 : out + (size_t)(b - 1) * N * 128;
        const u16* pb = packs + (size_t)b * 151552;
        tp_kernel<<<(N + 15) / 16, 256, 0, stream>>>(
            hidden + (size_t)b * N * 128, up, pb,
            lp_b0 + b * MULT, species, batch,
            S1 + b * NGRAPH, S2 + b * NGRAPH, V2 + b * NGRAPH,
            out + (size_t)b * N * 128, N);
        norm_kernel<<<(N + 7) / 8, 256, 0, stream>>>(
            hidden + (size_t)b * N * 128, out + (size_t)b * N * 128,
            sk_w0 + b * 1024, sk_b0 + b * MULT, sk_w1 + b * 1024,
            ln_w0 + b * MULT, ln_b0 + b * MULT, ln_w1 + b * MULT,
            batch, S1 + b * NGRAPH, S2 + b * NGRAPH, V2 + b * NGRAPH, cnt, N);
    }
}